// Round 1
// baseline (754.376 us; speedup 1.0000x reference)
//
#include <hip/hip_runtime.h>
#include <cstdint>

#define LDD 4096

typedef __attribute__((ext_vector_type(8))) short short8;   // 8 bf16 (4 VGPRs)
typedef __attribute__((ext_vector_type(4))) float f32x4;    // MFMA accumulator

// round-to-nearest-even fp32 -> bf16 (finite inputs only)
__device__ __forceinline__ short f2bf(float f) {
  uint32_t u = __builtin_bit_cast(uint32_t, f);
  u += 0x7fffu + ((u >> 16) & 1u);
  return (short)(u >> 16);
}

// async global->LDS, 16B per lane. LDS dest is wave-uniform base + lane*16;
// callers MUST compute lds addresses contiguous in lane order.
__device__ __forceinline__ void async16(const void* g, void* l) {
  __builtin_amdgcn_global_load_lds(
      (const __attribute__((address_space(1))) unsigned*)(uintptr_t)g,
      (__attribute__((address_space(3))) unsigned*)(uintptr_t)l,
      16, 0, 0);
}

// ---- prep: x fp32 -> x bf16 (row-major) + sq[i] = sum_f x[i,f]^2 (fp32) ----
__global__ __launch_bounds__(256)
void prep_rows(const float* __restrict__ x, short* __restrict__ xb,
               float* __restrict__ sq) {
  int row = blockIdx.x, tid = threadIdx.x;
  const float4* xr = (const float4*)(x + (size_t)row * LDD);
  short4* xo = (short4*)(xb + (size_t)row * LDD);
  float s = 0.f;
#pragma unroll
  for (int i = 0; i < 4; i++) {
    float4 v = xr[i * 256 + tid];
    s = fmaf(v.x, v.x, s); s = fmaf(v.y, v.y, s);
    s = fmaf(v.z, v.z, s); s = fmaf(v.w, v.w, s);
    short4 o; o.x = f2bf(v.x); o.y = f2bf(v.y); o.z = f2bf(v.z); o.w = f2bf(v.w);
    xo[i * 256 + tid] = o;
  }
#pragma unroll
  for (int off = 32; off > 0; off >>= 1) s += __shfl_down(s, off, 64);
  __shared__ float red[4];
  int lane = tid & 63, wv = tid >> 6;
  if (lane == 0) red[wv] = s;
  __syncthreads();
  if (tid == 0) sq[row] = red[0] + red[1] + red[2] + red[3];
}

// ---- transpose: x fp32 [B,F] -> xT bf16 [F,B], 64x64 LDS tiles ----
__global__ __launch_bounds__(256)
void transpose_bf16(const float* __restrict__ x, short* __restrict__ xT) {
  __shared__ float tile[64][65];
  int bx = blockIdx.x, by = blockIdx.y, tid = threadIdx.x;
  int tr = tid >> 4;          // 0..15
  int tc = (tid & 15) << 2;   // 0,4,..,60
#pragma unroll
  for (int i = 0; i < 4; i++) {
    int r = i * 16 + tr;
    float4 v = *(const float4*)(x + (size_t)(by * 64 + r) * LDD + bx * 64 + tc);
    tile[r][tc + 0] = v.x; tile[r][tc + 1] = v.y;
    tile[r][tc + 2] = v.z; tile[r][tc + 3] = v.w;
  }
  __syncthreads();
#pragma unroll
  for (int i = 0; i < 4; i++) {
    int fr = i * 16 + tr;     // f index within tile
    short4 o;
    o.x = f2bf(tile[tc + 0][fr]); o.y = f2bf(tile[tc + 1][fr]);
    o.z = f2bf(tile[tc + 2][fr]); o.w = f2bf(tile[tc + 3][fr]);
    *(short4*)(xT + (size_t)(bx * 64 + fr) * LDD + by * 64 + tc) = o;
  }
}

// ---- elementwise fp32 -> bf16 convert (W_out) ----
__global__ __launch_bounds__(256)
void conv_bf16(const float* __restrict__ w, short* __restrict__ wb) {
  int i = blockIdx.x * 256 + threadIdx.x;
  float4 v = ((const float4*)w)[i];
  short4 o; o.x = f2bf(v.x); o.y = f2bf(v.y); o.z = f2bf(v.z); o.w = f2bf(v.w);
  ((short4*)wb)[i] = o;
}

// ---- NT GEMM: C[M,N] = A[M,K] * Bt[N,K]^T, 128x128 tile, 16x16x32 bf16 MFMA.
// MODE 0: epilogue dist+exp -> bf16 gram (needs sq, Wrbf)
// MODE 1: epilogue bf16 cast -> outB
// MODE 2: epilogue + bias -> fp32 outF
template <int MODE>
__global__ __launch_bounds__(256)
void gemm_nt(const short* __restrict__ A, const short* __restrict__ Bt,
             short* __restrict__ outB, float* __restrict__ outF,
             const float* __restrict__ sq, const float* __restrict__ Wrbf,
             const float* __restrict__ bias) {
  __shared__ short As[128 * 32];  // 8 KB, row-major [m][k]
  __shared__ short Bs[128 * 32];  // 8 KB, row-major [n][k]
  int tid = threadIdx.x;
  int cb = blockIdx.x * 128;
  int rb = blockIdx.y * 128;

  // staging: thread -> (row tid/4 within 64-row group, 16B chunk tid%4)
  int sr = tid >> 2;
  int sc = (tid & 3) << 3;
  const short* Ag = A + (size_t)(rb + sr) * LDD + sc;
  const short* Bg = Bt + (size_t)(cb + sr) * LDD + sc;
  short* Al0 = As + sr * 32 + sc;
  short* Al1 = As + (64 + sr) * 32 + sc;
  short* Bl0 = Bs + sr * 32 + sc;
  short* Bl1 = Bs + (64 + sr) * 32 + sc;

  int lane = tid & 63;
  int wv = tid >> 6;
  int wm = wv >> 1, wn = wv & 1;      // 2x2 waves, each 64x64
  int fr = lane & 15;                 // m (A) / n (B) within 16-tile
  int fq = lane >> 4;                 // quad -> k-offset quad*8
  const short* Ar = As + (wm * 64 + fr) * 32 + fq * 8;
  const short* Br = Bs + (wn * 64 + fr) * 32 + fq * 8;

  f32x4 acc[4][4];
#pragma unroll
  for (int mi = 0; mi < 4; mi++)
#pragma unroll
    for (int ni = 0; ni < 4; ni++) acc[mi][ni] = {0.f, 0.f, 0.f, 0.f};

  for (int k0 = 0; k0 < LDD; k0 += 32) {
    __syncthreads();                       // all waves done reading prev tile
    async16(Ag + k0, Al0);
    async16(Ag + (size_t)64 * LDD + k0, Al1);
    async16(Bg + k0, Bl0);
    async16(Bg + (size_t)64 * LDD + k0, Bl1);
    __syncthreads();                       // vmcnt drain before use

    short8 av[4], bv[4];
#pragma unroll
    for (int mi = 0; mi < 4; mi++) av[mi] = *(const short8*)(Ar + mi * 16 * 32);
#pragma unroll
    for (int ni = 0; ni < 4; ni++) bv[ni] = *(const short8*)(Br + ni * 16 * 32);
#pragma unroll
    for (int mi = 0; mi < 4; mi++)
#pragma unroll
      for (int ni = 0; ni < 4; ni++)
        acc[mi][ni] = __builtin_amdgcn_mfma_f32_16x16x32_bf16(
            av[mi], bv[ni], acc[mi][ni], 0, 0, 0);
  }

  // epilogue: C/D layout col=lane&15, row=(lane>>4)*4+reg  [m89]
  int orow = rb + wm * 64 + fq * 4;
  int ocol = cb + wn * 64 + fr;

  float sqc[4], bc[4];
  if (MODE == 0) {
#pragma unroll
    for (int ni = 0; ni < 4; ni++) sqc[ni] = sq[ocol + ni * 16];
  }
  if (MODE == 2) {
#pragma unroll
    for (int ni = 0; ni < 4; ni++) bc[ni] = bias[ocol + ni * 16];
  }

#pragma unroll
  for (int mi = 0; mi < 4; mi++) {
#pragma unroll
    for (int r = 0; r < 4; r++) {
      int row = orow + mi * 16 + r;
      float sqr = (MODE == 0) ? sq[row] : 0.f;
#pragma unroll
      for (int ni = 0; ni < 4; ni++) {
        int col = ocol + ni * 16;
        size_t idx = (size_t)row * LDD + col;
        float v = acc[mi][ni][r];
        if (MODE == 0) {
          float d2 = sqr + sqc[ni] - 2.0f * v;
          d2 = fmaxf(d2, 0.0f);
          float dist = sqrtf(d2);
          float w = fabsf(Wrbf[idx]);
          outB[idx] = f2bf(__expf(-w * dist));
        } else if (MODE == 1) {
          outB[idx] = f2bf(v);
        } else {
          outF[idx] = v + bc[ni];
        }
      }
    }
  }
}

extern "C" void kernel_launch(void* const* d_in, const int* in_sizes, int n_in,
                              void* d_out, int out_size, void* d_ws, size_t ws_size,
                              hipStream_t stream) {
  const float* x    = (const float*)d_in[0];
  const float* Wrbf = (const float*)d_in[1];
  const float* Wout = (const float*)d_in[2];
  const float* bout = (const float*)d_in[3];
  float* out = (float*)d_out;

  // scratch layout:
  //   ws[0..32M)   : x bf16, later reused for mixed bf16
  //   ws[32M..64M) : sq (16KB, live only through gemm<0>), later W_out bf16
  //   d_out[0..32M)  : gram bf16   (dead before final gemm writes d_out)
  //   d_out[32M..64M): xT bf16     (dead before final gemm writes d_out)
  char* ws = (char*)d_ws;
  short* xb    = (short*)ws;                               // 32 MB
  float* sq    = (float*)(ws + (size_t)32 * 1024 * 1024);  // 16 KB
  short* woutb = (short*)(ws + (size_t)32 * 1024 * 1024);  // 32 MB (after gemm<0>)
  short* gram  = (short*)d_out;                            // 32 MB
  short* xT    = (short*)((char*)d_out + (size_t)32 * 1024 * 1024);  // 32 MB
  short* mixed = xb;                                       // reuse after gemm<0>

  prep_rows<<<LDD, 256, 0, stream>>>(x, xb, sq);
  transpose_bf16<<<dim3(64, 64), 256, 0, stream>>>(x, xT);
  // gram[i,j] = exp(-|Wrbf[i,j]| * ||x_i - x_j||)
  gemm_nt<0><<<dim3(32, 32), 256, 0, stream>>>(xb, xb, gram, nullptr, sq, Wrbf, nullptr);
  // mixed = gram @ x   (B^T operand = xT)
  gemm_nt<1><<<dim3(32, 32), 256, 0, stream>>>(gram, xT, mixed, nullptr, nullptr, nullptr, nullptr);
  conv_bf16<<<LDD * LDD / 4 / 256, 256, 0, stream>>>(Wout, woutb);
  // out = mixed @ W_out^T + b_out
  gemm_nt<2><<<dim3(32, 32), 256, 0, stream>>>(mixed, woutb, nullptr, out, nullptr, nullptr, bout);
}

// Round 2
// 721.935 us; speedup vs baseline: 1.0449x; 1.0449x over previous
//
#include <hip/hip_runtime.h>
#include <cstdint>

#define LDD 4096

typedef __attribute__((ext_vector_type(8))) short short8;   // 8 bf16 (4 VGPRs)
typedef __attribute__((ext_vector_type(4))) float f32x4;    // MFMA accumulator

// round-to-nearest-even fp32 -> bf16 (finite inputs only)
__device__ __forceinline__ short f2bf(float f) {
  uint32_t u = __builtin_bit_cast(uint32_t, f);
  u += 0x7fffu + ((u >> 16) & 1u);
  return (short)(u >> 16);
}

// async global->LDS, 16B per lane. LDS dest is wave-uniform base + lane*16.
__device__ __forceinline__ void async16(const void* g, void* l) {
  __builtin_amdgcn_global_load_lds(
      (const __attribute__((address_space(1))) unsigned*)(uintptr_t)g,
      (__attribute__((address_space(3))) unsigned*)(uintptr_t)l,
      16, 0, 0);
}

// ---- prep: x fp32 -> x bf16 (row-major) + sq[i] = sum_f x[i,f]^2 (fp32) ----
__global__ __launch_bounds__(256)
void prep_rows(const float* __restrict__ x, short* __restrict__ xb,
               float* __restrict__ sq) {
  int row = blockIdx.x, tid = threadIdx.x;
  const float4* xr = (const float4*)(x + (size_t)row * LDD);
  short4* xo = (short4*)(xb + (size_t)row * LDD);
  float s = 0.f;
#pragma unroll
  for (int i = 0; i < 4; i++) {
    float4 v = xr[i * 256 + tid];
    s = fmaf(v.x, v.x, s); s = fmaf(v.y, v.y, s);
    s = fmaf(v.z, v.z, s); s = fmaf(v.w, v.w, s);
    short4 o; o.x = f2bf(v.x); o.y = f2bf(v.y); o.z = f2bf(v.z); o.w = f2bf(v.w);
    xo[i * 256 + tid] = o;
  }
#pragma unroll
  for (int off = 32; off > 0; off >>= 1) s += __shfl_down(s, off, 64);
  __shared__ float red[4];
  int lane = tid & 63, wv = tid >> 6;
  if (lane == 0) red[wv] = s;
  __syncthreads();
  if (tid == 0) sq[row] = red[0] + red[1] + red[2] + red[3];
}

// ---- transpose: x fp32 [B,F] -> xT bf16 [F,B], 64x64 LDS tiles ----
__global__ __launch_bounds__(256)
void transpose_bf16(const float* __restrict__ x, short* __restrict__ xT) {
  __shared__ float tile[64][65];
  int bx = blockIdx.x, by = blockIdx.y, tid = threadIdx.x;
  int tr = tid >> 4;          // 0..15
  int tc = (tid & 15) << 2;   // 0,4,..,60
#pragma unroll
  for (int i = 0; i < 4; i++) {
    int r = i * 16 + tr;
    float4 v = *(const float4*)(x + (size_t)(by * 64 + r) * LDD + bx * 64 + tc);
    tile[r][tc + 0] = v.x; tile[r][tc + 1] = v.y;
    tile[r][tc + 2] = v.z; tile[r][tc + 3] = v.w;
  }
  __syncthreads();
#pragma unroll
  for (int i = 0; i < 4; i++) {
    int fr = i * 16 + tr;     // f index within tile
    short4 o;
    o.x = f2bf(tile[tc + 0][fr]); o.y = f2bf(tile[tc + 1][fr]);
    o.z = f2bf(tile[tc + 2][fr]); o.w = f2bf(tile[tc + 3][fr]);
    *(short4*)(xT + (size_t)(bx * 64 + fr) * LDD + by * 64 + tc) = o;
  }
}

// ---- elementwise fp32 -> bf16 convert (W_out) ----
__global__ __launch_bounds__(256)
void conv_bf16(const float* __restrict__ w, short* __restrict__ wb) {
  int i = blockIdx.x * 256 + threadIdx.x;
  float4 v = ((const float4*)w)[i];
  short4 o; o.x = f2bf(v.x); o.y = f2bf(v.y); o.z = f2bf(v.z); o.w = f2bf(v.w);
  ((short4*)wb)[i] = o;
}

// ---- NT GEMM: C[M,N] = A[M,K] * Bt[N,K]^T, 128x128 tile, 16x16x32 bf16 MFMA.
// Double-buffered LDS (one barrier/iter, loads issued a full phase ahead).
// LDS chunk swizzle: slot s of row l holds global chunk (s - (l>>1))&3 so the
// fragment ds_read_b128 pattern is 2-way bank-aliased (free) instead of 8-way.
// MODE 0: epilogue dist+exp -> bf16 gram (needs sq, Wrbf)
// MODE 1: epilogue bf16 cast -> outB
// MODE 2: epilogue + bias -> fp32 outF
template <int MODE>
__global__ __launch_bounds__(256)
void gemm_nt(const short* __restrict__ A, const short* __restrict__ Bt,
             short* __restrict__ outB, float* __restrict__ outF,
             const float* __restrict__ sq, const float* __restrict__ Wrbf,
             const float* __restrict__ bias) {
  __shared__ short As[2][4096];  // 2 x 8 KB: [l=0..127][slot 0..3][8 shorts]
  __shared__ short Bs[2][4096];
  int tid = threadIdx.x;
  int cb = blockIdx.x * 128;
  int rb = blockIdx.y * 128;

  // staging: lane tid -> LDS bytes [tid*16, tid*16+16) of each 64-row group
  // (hardware-fixed). Global source chunk is swizzled: row sr, chunk
  // ((tid&3) - (sr>>1)) & 3.
  int sr = tid >> 2;                                    // row within 64-group
  int schunk = ((tid & 3) - ((tid >> 3) & 3)) & 3;      // swizzled 16B chunk
  const short* Ag = A + (size_t)(rb + sr) * LDD + (schunk << 3);
  const short* Bg = Bt + (size_t)(cb + sr) * LDD + (schunk << 3);
  int ldst = tid * 8;                                   // shorts; group0 dest

  int lane = tid & 63;
  int wv = tid >> 6;
  int wm = wv >> 1, wn = wv & 1;      // 2x2 waves, each 64x64
  int fr = lane & 15;                 // m (A) / n (B) within 16-tile
  int fq = lane >> 4;                 // quad -> k-offset quad*8
  // fragment read offset (shorts), swizzled slot = (fq + (fr>>1)) & 3
  int slot = (fq + (fr >> 1)) & 3;
  int aoff = (wm * 64 + fr) * 32 + slot * 8;
  int boff = (wn * 64 + fr) * 32 + slot * 8;

  f32x4 acc[4][4];
#pragma unroll
  for (int mi = 0; mi < 4; mi++)
#pragma unroll
    for (int ni = 0; ni < 4; ni++) acc[mi][ni] = {0.f, 0.f, 0.f, 0.f};

  // prologue: stage tile 0 into buffer 0
  async16(Ag, &As[0][ldst]);
  async16(Ag + (size_t)64 * LDD, &As[0][2048 + ldst]);
  async16(Bg, &Bs[0][ldst]);
  async16(Bg + (size_t)64 * LDD, &Bs[0][2048 + ldst]);

  int buf = 0;
  for (int k0 = 0; k0 < LDD; k0 += 32) {
    __syncthreads();  // publishes tile k0 (vmcnt drain; loads had a full phase)
    int nbuf = buf ^ 1;
    if (k0 + 32 < LDD) {
      async16(Ag + k0 + 32, &As[nbuf][ldst]);
      async16(Ag + (size_t)64 * LDD + k0 + 32, &As[nbuf][2048 + ldst]);
      async16(Bg + k0 + 32, &Bs[nbuf][ldst]);
      async16(Bg + (size_t)64 * LDD + k0 + 32, &Bs[nbuf][2048 + ldst]);
    }

    const short* Ar = &As[buf][aoff];
    const short* Br = &Bs[buf][boff];
    short8 av[4], bv[4];
#pragma unroll
    for (int mi = 0; mi < 4; mi++) av[mi] = *(const short8*)(Ar + mi * 16 * 32);
#pragma unroll
    for (int ni = 0; ni < 4; ni++) bv[ni] = *(const short8*)(Br + ni * 16 * 32);
#pragma unroll
    for (int mi = 0; mi < 4; mi++)
#pragma unroll
      for (int ni = 0; ni < 4; ni++)
        acc[mi][ni] = __builtin_amdgcn_mfma_f32_16x16x32_bf16(
            av[mi], bv[ni], acc[mi][ni], 0, 0, 0);
    buf = nbuf;
  }

  // epilogue: C/D layout col=lane&15, row=(lane>>4)*4+reg  [m89]
  int orow = rb + wm * 64 + fq * 4;
  int ocol = cb + wn * 64 + fr;

  float sqc[4], bc[4];
  if (MODE == 0) {
#pragma unroll
    for (int ni = 0; ni < 4; ni++) sqc[ni] = sq[ocol + ni * 16];
  }
  if (MODE == 2) {
#pragma unroll
    for (int ni = 0; ni < 4; ni++) bc[ni] = bias[ocol + ni * 16];
  }

#pragma unroll
  for (int mi = 0; mi < 4; mi++) {
#pragma unroll
    for (int r = 0; r < 4; r++) {
      int row = orow + mi * 16 + r;
      float sqr = (MODE == 0) ? sq[row] : 0.f;
#pragma unroll
      for (int ni = 0; ni < 4; ni++) {
        int col = ocol + ni * 16;
        size_t idx = (size_t)row * LDD + col;
        float v = acc[mi][ni][r];
        if (MODE == 0) {
          float d2 = sqr + sqc[ni] - 2.0f * v;
          d2 = fmaxf(d2, 0.0f);
          float dist = sqrtf(d2);
          float w = fabsf(Wrbf[idx]);
          outB[idx] = f2bf(__expf(-w * dist));
        } else if (MODE == 1) {
          outB[idx] = f2bf(v);
        } else {
          outF[idx] = v + bc[ni];
        }
      }
    }
  }
}

extern "C" void kernel_launch(void* const* d_in, const int* in_sizes, int n_in,
                              void* d_out, int out_size, void* d_ws, size_t ws_size,
                              hipStream_t stream) {
  const float* x    = (const float*)d_in[0];
  const float* Wrbf = (const float*)d_in[1];
  const float* Wout = (const float*)d_in[2];
  const float* bout = (const float*)d_in[3];
  float* out = (float*)d_out;

  // scratch layout:
  //   ws[0..32M)   : x bf16, later reused for mixed bf16
  //   ws[32M..64M) : sq (16KB, live only through gemm<0>), later W_out bf16
  //   d_out[0..32M)  : gram bf16   (dead before final gemm writes d_out)
  //   d_out[32M..64M): xT bf16     (dead before final gemm writes d_out)
  char* ws = (char*)d_ws;
  short* xb    = (short*)ws;                               // 32 MB
  float* sq    = (float*)(ws + (size_t)32 * 1024 * 1024);  // 16 KB
  short* woutb = (short*)(ws + (size_t)32 * 1024 * 1024);  // 32 MB (after gemm<0>)
  short* gram  = (short*)d_out;                            // 32 MB
  short* xT    = (short*)((char*)d_out + (size_t)32 * 1024 * 1024);  // 32 MB
  short* mixed = xb;                                       // reuse after gemm<0>

  prep_rows<<<LDD, 256, 0, stream>>>(x, xb, sq);
  transpose_bf16<<<dim3(64, 64), 256, 0, stream>>>(x, xT);
  // gram[i,j] = exp(-|Wrbf[i,j]| * ||x_i - x_j||)
  gemm_nt<0><<<dim3(32, 32), 256, 0, stream>>>(xb, xb, gram, nullptr, sq, Wrbf, nullptr);
  // mixed = gram @ x   (B^T operand = xT)
  gemm_nt<1><<<dim3(32, 32), 256, 0, stream>>>(gram, xT, mixed, nullptr, nullptr, nullptr, nullptr);
  conv_bf16<<<LDD * LDD / 4 / 256, 256, 0, stream>>>(Wout, woutb);
  // out = mixed @ W_out^T + b_out
  gemm_nt<2><<<dim3(32, 32), 256, 0, stream>>>(mixed, woutb, nullptr, out, nullptr, nullptr, bout);
}

// Round 3
// 710.525 us; speedup vs baseline: 1.0617x; 1.0161x over previous
//
#include <hip/hip_runtime.h>
#include <cstdint>

#define LDD 4096

typedef __attribute__((ext_vector_type(8))) short short8;   // 8 bf16 (4 VGPRs)
typedef __attribute__((ext_vector_type(4))) float f32x4;    // MFMA accumulator

// round-to-nearest-even fp32 -> bf16 (finite inputs only)
__device__ __forceinline__ short f2bf(float f) {
  uint32_t u = __builtin_bit_cast(uint32_t, f);
  u += 0x7fffu + ((u >> 16) & 1u);
  return (short)(u >> 16);
}

// async global->LDS, 16B per lane. LDS dest is wave-uniform base + lane*16.
__device__ __forceinline__ void async16(const void* g, void* l) {
  __builtin_amdgcn_global_load_lds(
      (const __attribute__((address_space(1))) unsigned*)(uintptr_t)g,
      (__attribute__((address_space(3))) unsigned*)(uintptr_t)l,
      16, 0, 0);
}

// ---- prep: x fp32 -> x bf16 (row-major) + sq[i] = sum_f x[i,f]^2 (fp32) ----
__global__ __launch_bounds__(256)
void prep_rows(const float* __restrict__ x, short* __restrict__ xb,
               float* __restrict__ sq) {
  int row = blockIdx.x, tid = threadIdx.x;
  const float4* xr = (const float4*)(x + (size_t)row * LDD);
  short4* xo = (short4*)(xb + (size_t)row * LDD);
  float s = 0.f;
#pragma unroll
  for (int i = 0; i < 4; i++) {
    float4 v = xr[i * 256 + tid];
    s = fmaf(v.x, v.x, s); s = fmaf(v.y, v.y, s);
    s = fmaf(v.z, v.z, s); s = fmaf(v.w, v.w, s);
    short4 o; o.x = f2bf(v.x); o.y = f2bf(v.y); o.z = f2bf(v.z); o.w = f2bf(v.w);
    xo[i * 256 + tid] = o;
  }
#pragma unroll
  for (int off = 32; off > 0; off >>= 1) s += __shfl_down(s, off, 64);
  __shared__ float red[4];
  int lane = tid & 63, wv = tid >> 6;
  if (lane == 0) red[wv] = s;
  __syncthreads();
  if (tid == 0) sq[row] = red[0] + red[1] + red[2] + red[3];
}

// ---- transpose: x fp32 [B,F] -> xT bf16 [F,B], 64x64 LDS tiles ----
__global__ __launch_bounds__(256)
void transpose_bf16(const float* __restrict__ x, short* __restrict__ xT) {
  __shared__ float tile[64][65];
  int bx = blockIdx.x, by = blockIdx.y, tid = threadIdx.x;
  int tr = tid >> 4;          // 0..15
  int tc = (tid & 15) << 2;   // 0,4,..,60
#pragma unroll
  for (int i = 0; i < 4; i++) {
    int r = i * 16 + tr;
    float4 v = *(const float4*)(x + (size_t)(by * 64 + r) * LDD + bx * 64 + tc);
    tile[r][tc + 0] = v.x; tile[r][tc + 1] = v.y;
    tile[r][tc + 2] = v.z; tile[r][tc + 3] = v.w;
  }
  __syncthreads();
#pragma unroll
  for (int i = 0; i < 4; i++) {
    int fr = i * 16 + tr;     // f index within tile
    short4 o;
    o.x = f2bf(tile[tc + 0][fr]); o.y = f2bf(tile[tc + 1][fr]);
    o.z = f2bf(tile[tc + 2][fr]); o.w = f2bf(tile[tc + 3][fr]);
    *(short4*)(xT + (size_t)(bx * 64 + fr) * LDD + by * 64 + tc) = o;
  }
}

// ---- elementwise fp32 -> bf16 convert (W_out) ----
__global__ __launch_bounds__(256)
void conv_bf16(const float* __restrict__ w, short* __restrict__ wb) {
  int i = blockIdx.x * 256 + threadIdx.x;
  float4 v = ((const float4*)w)[i];
  short4 o; o.x = f2bf(v.x); o.y = f2bf(v.y); o.z = f2bf(v.z); o.w = f2bf(v.w);
  ((short4*)wb)[i] = o;
}

// ---- NT GEMM (modes 1,2): C[M,N] = A[M,K] * Bt[N,K]^T, 128x128 tile.
// Double-buffered LDS, 16B-chunk swizzle (conflict-free, verified R2).
// MODE 1: epilogue bf16 cast -> outB;  MODE 2: epilogue + bias -> fp32 outF
template <int MODE>
__global__ __launch_bounds__(256)
void gemm_nt(const short* __restrict__ A, const short* __restrict__ Bt,
             short* __restrict__ outB, float* __restrict__ outF,
             const float* __restrict__ bias) {
  __shared__ short As[2][4096];
  __shared__ short Bs[2][4096];
  int tid = threadIdx.x;
  int cb = blockIdx.x * 128;
  int rb = blockIdx.y * 128;

  int sr = tid >> 2;
  int schunk = ((tid & 3) - ((tid >> 3) & 3)) & 3;      // swizzled 16B chunk
  const short* Ag = A + (size_t)(rb + sr) * LDD + (schunk << 3);
  const short* Bg = Bt + (size_t)(cb + sr) * LDD + (schunk << 3);
  int ldst = tid * 8;

  int lane = tid & 63;
  int wv = tid >> 6;
  int wm = wv >> 1, wn = wv & 1;
  int fr = lane & 15;
  int fq = lane >> 4;
  int slot = (fq + (fr >> 1)) & 3;
  int aoff = (wm * 64 + fr) * 32 + slot * 8;
  int boff = (wn * 64 + fr) * 32 + slot * 8;

  f32x4 acc[4][4];
#pragma unroll
  for (int mi = 0; mi < 4; mi++)
#pragma unroll
    for (int ni = 0; ni < 4; ni++) acc[mi][ni] = {0.f, 0.f, 0.f, 0.f};

  async16(Ag, &As[0][ldst]);
  async16(Ag + (size_t)64 * LDD, &As[0][2048 + ldst]);
  async16(Bg, &Bs[0][ldst]);
  async16(Bg + (size_t)64 * LDD, &Bs[0][2048 + ldst]);

  int buf = 0;
  for (int k0 = 0; k0 < LDD; k0 += 32) {
    __syncthreads();
    int nbuf = buf ^ 1;
    if (k0 + 32 < LDD) {
      async16(Ag + k0 + 32, &As[nbuf][ldst]);
      async16(Ag + (size_t)64 * LDD + k0 + 32, &As[nbuf][2048 + ldst]);
      async16(Bg + k0 + 32, &Bs[nbuf][ldst]);
      async16(Bg + (size_t)64 * LDD + k0 + 32, &Bs[nbuf][2048 + ldst]);
    }
    const short* Ar = &As[buf][aoff];
    const short* Br = &Bs[buf][boff];
    short8 av[4], bv[4];
#pragma unroll
    for (int mi = 0; mi < 4; mi++) av[mi] = *(const short8*)(Ar + mi * 16 * 32);
#pragma unroll
    for (int ni = 0; ni < 4; ni++) bv[ni] = *(const short8*)(Br + ni * 16 * 32);
#pragma unroll
    for (int mi = 0; mi < 4; mi++)
#pragma unroll
      for (int ni = 0; ni < 4; ni++)
        acc[mi][ni] = __builtin_amdgcn_mfma_f32_16x16x32_bf16(
            av[mi], bv[ni], acc[mi][ni], 0, 0, 0);
    buf = nbuf;
  }

  int orow = rb + wm * 64 + fq * 4;
  int ocol = cb + wn * 64 + fr;
  float bc[4];
  if (MODE == 2) {
#pragma unroll
    for (int ni = 0; ni < 4; ni++) bc[ni] = bias[ocol + ni * 16];
  }
#pragma unroll
  for (int mi = 0; mi < 4; mi++) {
#pragma unroll
    for (int r = 0; r < 4; r++) {
      int row = orow + mi * 16 + r;
#pragma unroll
      for (int ni = 0; ni < 4; ni++) {
        size_t idx = (size_t)row * LDD + ocol + ni * 16;
        float v = acc[mi][ni][r];
        if (MODE == 1) outB[idx] = f2bf(v);
        else           outF[idx] = v + bc[ni];
      }
    }
  }
}

// ---- Symmetric gram GEMM: only upper-triangle tiles (528 blocks).
// dot(x_i,x_j) is symmetric; |W| is not. Off-diag blocks write both
// gram[i,j] (direct) and gram[j,i] (dist transposed via LDS fp16).
__global__ __launch_bounds__(256)
void gemm_sym(const short* __restrict__ A,
              short* __restrict__ gram,
              const float* __restrict__ sq, const float* __restrict__ Wrbf) {
  __shared__ __align__(16) char smem[33280];  // union: staging 32KB | dT 33280B
  short* As = (short*)smem;                 // As[buf*4096 + i]
  short* Bs = (short*)(smem + 16384);       // Bs[buf*4096 + i]
  unsigned short* T = (unsigned short*)smem; // dT fp16 [128][130]

  // upper-triangle mapping: t -> (bi, bj), bi<=bj; offset(bi)=bi*(65-bi)/2
  int t = blockIdx.x;
  int bi = (int)((65.0f - sqrtf((float)(4225 - 8 * t))) * 0.5f);
  while (((bi + 1) * (65 - (bi + 1))) / 2 <= t) bi++;
  while ((bi * (65 - bi)) / 2 > t) bi--;
  int bj = bi + (t - (bi * (65 - bi)) / 2);
  int rb = bi * 128, cb = bj * 128;
  bool diag = (bi == bj);

  int tid = threadIdx.x;
  int sr = tid >> 2;
  int schunk = ((tid & 3) - ((tid >> 3) & 3)) & 3;
  const short* Ag = A + (size_t)(rb + sr) * LDD + (schunk << 3);
  const short* Bg = A + (size_t)(cb + sr) * LDD + (schunk << 3);
  int ldst = tid * 8;

  int lane = tid & 63;
  int wv = tid >> 6;
  int wm = wv >> 1, wn = wv & 1;
  int fr = lane & 15;
  int fq = lane >> 4;
  int slot = (fq + (fr >> 1)) & 3;
  int aoff = (wm * 64 + fr) * 32 + slot * 8;
  int boff = (wn * 64 + fr) * 32 + slot * 8;

  f32x4 acc[4][4];
#pragma unroll
  for (int mi = 0; mi < 4; mi++)
#pragma unroll
    for (int ni = 0; ni < 4; ni++) acc[mi][ni] = {0.f, 0.f, 0.f, 0.f};

  async16(Ag, &As[ldst]);
  async16(Ag + (size_t)64 * LDD, &As[2048 + ldst]);
  async16(Bg, &Bs[ldst]);
  async16(Bg + (size_t)64 * LDD, &Bs[2048 + ldst]);

  int buf = 0;
  for (int k0 = 0; k0 < LDD; k0 += 32) {
    __syncthreads();
    int nbuf = buf ^ 1;
    if (k0 + 32 < LDD) {
      async16(Ag + k0 + 32, &As[nbuf * 4096 + ldst]);
      async16(Ag + (size_t)64 * LDD + k0 + 32, &As[nbuf * 4096 + 2048 + ldst]);
      async16(Bg + k0 + 32, &Bs[nbuf * 4096 + ldst]);
      async16(Bg + (size_t)64 * LDD + k0 + 32, &Bs[nbuf * 4096 + 2048 + ldst]);
    }
    const short* Ar = &As[buf * 4096 + aoff];
    const short* Br = &Bs[buf * 4096 + boff];
    short8 av[4], bv[4];
#pragma unroll
    for (int mi = 0; mi < 4; mi++) av[mi] = *(const short8*)(Ar + mi * 16 * 32);
#pragma unroll
    for (int ni = 0; ni < 4; ni++) bv[ni] = *(const short8*)(Br + ni * 16 * 32);
#pragma unroll
    for (int mi = 0; mi < 4; mi++)
#pragma unroll
      for (int ni = 0; ni < 4; ni++)
        acc[mi][ni] = __builtin_amdgcn_mfma_f32_16x16x32_bf16(
            av[mi], bv[ni], acc[mi][ni], 0, 0, 0);
    buf = nbuf;
  }

  // local epilogue coordinates (within 128x128 tile)
  int lrow0 = wm * 64 + fq * 4;       // + mi*16 + r
  int lcol0 = wn * 64 + fr;           // + ni*16

  float sqc[4];
#pragma unroll
  for (int ni = 0; ni < 4; ni++) sqc[ni] = sq[cb + lcol0 + ni * 16];

  __syncthreads();  // staging LDS reads done everywhere; safe to reuse as T

  // pass 1: direct tile gram[rb+lr, cb+lc]; stash d (fp16) transposed in LDS
#pragma unroll
  for (int mi = 0; mi < 4; mi++) {
#pragma unroll
    for (int r = 0; r < 4; r++) {
      int lr = lrow0 + mi * 16 + r;
      float sqr = sq[rb + lr];
#pragma unroll
      for (int ni = 0; ni < 4; ni++) {
        int lc = lcol0 + ni * 16;
        float d2 = sqr + sqc[ni] - 2.0f * acc[mi][ni][r];
        float d = sqrtf(fmaxf(d2, 0.0f));
        size_t idx = (size_t)(rb + lr) * LDD + cb + lc;
        outb:;
        gram[idx] = f2bf(__expf(-fabsf(Wrbf[idx]) * d));
        if (!diag) T[lc * 130 + lr] = __builtin_bit_cast(unsigned short, (_Float16)d);
      }
    }
  }

  if (diag) return;
  __syncthreads();

  // pass 2: mirror tile gram[cb+a, rb+b] with d from T[a*130+b]
#pragma unroll
  for (int mi = 0; mi < 4; mi++) {
#pragma unroll
    for (int r = 0; r < 4; r++) {
      int a = lrow0 + mi * 16 + r;
#pragma unroll
      for (int ni = 0; ni < 4; ni++) {
        int b = lcol0 + ni * 16;
        float d = (float)__builtin_bit_cast(_Float16, T[a * 130 + b]);
        size_t idx = (size_t)(cb + a) * LDD + rb + b;
        gram[idx] = f2bf(__expf(-fabsf(Wrbf[idx]) * d));
      }
    }
  }
}

extern "C" void kernel_launch(void* const* d_in, const int* in_sizes, int n_in,
                              void* d_out, int out_size, void* d_ws, size_t ws_size,
                              hipStream_t stream) {
  const float* x    = (const float*)d_in[0];
  const float* Wrbf = (const float*)d_in[1];
  const float* Wout = (const float*)d_in[2];
  const float* bout = (const float*)d_in[3];
  float* out = (float*)d_out;

  char* ws = (char*)d_ws;
  short* xb    = (short*)ws;                               // 32 MB
  float* sq    = (float*)(ws + (size_t)32 * 1024 * 1024);  // 16 KB
  short* woutb = (short*)(ws + (size_t)32 * 1024 * 1024);  // 32 MB (after gemm_sym)
  short* gram  = (short*)d_out;                            // 32 MB
  short* xT    = (short*)((char*)d_out + (size_t)32 * 1024 * 1024);  // 32 MB
  short* mixed = xb;                                       // reuse after gemm_sym

  prep_rows<<<LDD, 256, 0, stream>>>(x, xb, sq);
  transpose_bf16<<<dim3(64, 64), 256, 0, stream>>>(x, xT);
  // gram[i,j] = exp(-|Wrbf[i,j]| * ||x_i - x_j||), upper triangle + mirror
  gemm_sym<<<528, 256, 0, stream>>>(xb, gram, sq, Wrbf);
  // mixed = gram @ x   (B^T operand = xT)
  gemm_nt<1><<<dim3(32, 32), 256, 0, stream>>>(gram, xT, mixed, nullptr, nullptr);
  conv_bf16<<<LDD * LDD / 4 / 256, 256, 0, stream>>>(Wout, woutb);
  // out = mixed @ W_out^T + b_out
  gemm_nt<2><<<dim3(32, 32), 256, 0, stream>>>(mixed, woutb, nullptr, out, bout);
}